// Round 1
// baseline (357.935 us; speedup 1.0000x reference)
//
#include <hip/hip_runtime.h>

#define W_ 352
#define H_ 128
#define HW 45056
#define D_ 48
#define B_ 2
#define N_ 6
#define DHW (D_*HW)          // 2,162,688
#define PC_SIZE (36*DHW)     // 77,856,768  (B*N*3 * D*HW)
#define BHW (B_*HW)          // 90,112
#define BEVN (B_*64*HW)      // 5,767,168

// ws float offsets
#define WS_KINV 0     // 12*9 = 108
#define WS_DA   128   // 48
#define WS_SUM1 192
#define WS_SQ1  256
#define WS_SC1  320
#define WS_SH1  384
#define WS_SUM2 448
#define WS_SQ2  512
#define WS_SC2  576
#define WS_SH2  640
// total 704 floats (2816 B)

// ---------------- prep: 3x3 inverses, depth softmax, zero accumulators ----
__global__ void k_prep(const float* __restrict__ K4, const float* __restrict__ datt,
                       float* __restrict__ ws) {
    int t = threadIdx.x;
    for (int i = WS_SUM1 + t; i < WS_SC2 + 64; i += 256) ws[i] = 0.f;  // zero 192..639
    if (t < 12) {
        const float* M = K4 + t * 16;
        float a = M[0], b = M[1], c = M[2];
        float d = M[4], e = M[5], f = M[6];
        float g = M[8], h = M[9], ii = M[10];
        float det = a*(e*ii - f*h) - b*(d*ii - f*g) + c*(d*h - e*g);
        float inv = 1.f / det;
        float* o = ws + WS_KINV + t * 9;
        o[0] = (e*ii - f*h)*inv; o[1] = (c*h - b*ii)*inv; o[2] = (b*f - c*e)*inv;
        o[3] = (f*g - d*ii)*inv; o[4] = (a*ii - c*g)*inv; o[5] = (c*d - a*f)*inv;
        o[6] = (d*h - e*g)*inv;  o[7] = (b*g - a*h)*inv;  o[8] = (a*e - b*d)*inv;
    }
    if (t == 0) {
        float mx = -1e30f;
        for (int k = 0; k < D_; k++) mx = fmaxf(mx, datt[k]);
        float s = 0.f, e[D_];
        for (int k = 0; k < D_; k++) { e[k] = expf(datt[k] - mx); s += e[k]; }
        float invs = 1.f / s;
        for (int k = 0; k < D_; k++) ws[WS_DA + k] = e[k] * invs;
    }
}

// ---------------- pc writer (the big 311MB streaming store) ----------------
__global__ __launch_bounds__(256) void k_pc(const float* __restrict__ depths,
                                            const float* __restrict__ ws,
                                            float* __restrict__ out) {
    int t = blockIdx.x * 256 + threadIdx.x;
    int f = t * 4;
    if (f >= PC_SIZE) return;
    int bnc = f / DHW;                  // 0..35  (= bn*3 + c)
    int r1  = f - bnc * DHW;
    int d   = r1 / HW;
    int p   = r1 - d * HW;
    int y   = p / W_;
    int x   = p - y * W_;
    float ka = ws[WS_KINV + bnc*3 + 0];
    float kb = ws[WS_KINV + bnc*3 + 1];
    float kc = ws[WS_KINV + bnc*3 + 2];
    float dep = depths[d];
    float base = fmaf(kb, (float)y, kc);
    float4 v;
    v.x = dep * fmaf(ka, (float)(x + 0), base);
    v.y = dep * fmaf(ka, (float)(x + 1), base);
    v.z = dep * fmaf(ka, (float)(x + 2), base);
    v.w = dep * fmaf(ka, (float)(x + 3), base);
    *(float4*)(out + f) = v;
}

// ---------------- bev_features = einsum('bnchwd,d,nhw->bchw') --------------
__global__ __launch_bounds__(256) void k_bevf(const float* __restrict__ vatt,
                                              const float* __restrict__ depths,
                                              const float* __restrict__ ws,
                                              float* __restrict__ bevf) {
    int pix = blockIdx.x * 256 + threadIdx.x;   // < 90112
    int b = pix / HW;
    int rem = pix - b * HW;
    // softmax over N views at this pixel
    float v[N_]; float mx = -1e30f;
    for (int n = 0; n < N_; n++) { v[n] = vatt[n * HW + rem]; mx = fmaxf(mx, v[n]); }
    float s = 0.f;
    for (int n = 0; n < N_; n++) { v[n] = expf(v[n] - mx); s += v[n]; }
    float invs = 1.f / s;
    float acc0 = 0.f, acc1 = 0.f, acc2 = 0.f;
    int base = rem * D_;
    for (int n = 0; n < N_; n++) {
        float van = v[n] * invs;
        const float* kv = ws + WS_KINV + (b * N_ + n) * 9;
        float a0 = kv[0], a1 = kv[1], a2 = kv[2];
        float b0 = kv[3], b1 = kv[4], b2 = kv[5];
        float c0 = kv[6], c1 = kv[7], c2 = kv[8];
        for (int dd = 0; dd < D_; dd++) {
            int q = base + dd;
            int d = q / HW;
            int p = q - d * HW;
            int yy = p / W_;
            int xx = p - yy * W_;
            float wq = van * ws[WS_DA + dd] * depths[d];
            float fx = (float)xx, fy = (float)yy;
            acc0 += wq * fmaf(a0, fx, fmaf(a1, fy, a2));
            acc1 += wq * fmaf(b0, fx, fmaf(b1, fy, b2));
            acc2 += wq * fmaf(c0, fx, fmaf(c1, fy, c2));
        }
    }
    bevf[(b * 3 + 0) * HW + rem] = acc0;
    bevf[(b * 3 + 1) * HW + rem] = acc1;
    bevf[(b * 3 + 2) * HW + rem] = acc2;
}

// ---------------- conv1: 3 -> 64, 3x3 SAME -------------------------------
__global__ __launch_bounds__(256) void k_conv1(const float* __restrict__ bevf,
                                               const float* __restrict__ w1,
                                               const float* __restrict__ b1,
                                               float* __restrict__ h1) {
    __shared__ float wl[64 * 27];
    for (int i = threadIdx.x; i < 64 * 27; i += 256) wl[i] = w1[i];
    __syncthreads();
    int pix = blockIdx.x * 256 + threadIdx.x;
    int b = pix / HW;
    int rem = pix - b * HW;
    int h = rem / W_;
    int w = rem - h * W_;
    float v[27];
    #pragma unroll
    for (int ci = 0; ci < 3; ci++)
        #pragma unroll
        for (int dy = 0; dy < 3; dy++)
            #pragma unroll
            for (int dx = 0; dx < 3; dx++) {
                int hh = h + dy - 1, ww = w + dx - 1;
                float val = 0.f;
                if (hh >= 0 && hh < H_ && ww >= 0 && ww < W_)
                    val = bevf[(b * 3 + ci) * HW + hh * W_ + ww];
                v[ci * 9 + dy * 3 + dx] = val;
            }
    for (int co = 0; co < 64; co++) {
        float acc = b1[co];
        #pragma unroll
        for (int k = 0; k < 27; k++) acc = fmaf(wl[co * 27 + k], v[k], acc);
        h1[(b * 64 + co) * HW + rem] = acc;
    }
}

// ---------------- per-channel sum / sumsq (for BN training stats) ---------
__global__ __launch_bounds__(256) void k_stats(const float* __restrict__ x,
                                               float* __restrict__ ws,
                                               int sumOff, int sqOff) {
    int c = blockIdx.x >> 3;       // 64 channels
    int slice = blockIdx.x & 7;    // 8 slices of 11264 each (8*11264 = 90112)
    float s = 0.f, sq = 0.f;
    int j0 = slice * 11264;
    for (int i = threadIdx.x; i < 11264; i += 256) {
        int j = j0 + i;
        int b = (j >= HW) ? 1 : 0;
        float val = x[(b * 64 + c) * HW + (j - b * HW)];
        s += val;
        sq = fmaf(val, val, sq);
    }
    __shared__ float ls[256], lq[256];
    ls[threadIdx.x] = s; lq[threadIdx.x] = sq;
    __syncthreads();
    for (int st = 128; st > 0; st >>= 1) {
        if (threadIdx.x < st) {
            ls[threadIdx.x] += ls[threadIdx.x + st];
            lq[threadIdx.x] += lq[threadIdx.x + st];
        }
        __syncthreads();
    }
    if (threadIdx.x == 0) {
        atomicAdd(ws + sumOff + c, ls[0]);
        atomicAdd(ws + sqOff + c, lq[0]);
    }
}

// ---------------- finalize BN scale/shift ---------------------------------
__global__ void k_fin(const float* __restrict__ g, const float* __restrict__ bb,
                      float* __restrict__ ws, int sumOff, int sqOff, int scOff, int shOff) {
    int c = threadIdx.x;
    if (c >= 64) return;
    const float invM = 1.f / (float)BHW;
    float m = ws[sumOff + c] * invM;
    float var = ws[sqOff + c] * invM - m * m;
    float sc = g[c] / sqrtf(var + 1e-5f);
    ws[scOff + c] = sc;
    ws[shOff + c] = bb[c] - m * sc;
}

// ---------------- conv2: 64 -> 64, 3x3, with BN1+ReLU fused on input ------
__global__ __launch_bounds__(256) void k_conv2(const float* __restrict__ h1,
                                               const float* __restrict__ w2,
                                               const float* __restrict__ b2,
                                               const float* __restrict__ ws,
                                               float* __restrict__ h2) {
    int cog = blockIdx.y * 16;     // output-channel group
    int pix = blockIdx.x * 256 + threadIdx.x;
    int b = pix / HW;
    int rem = pix - b * HW;
    int h = rem / W_;
    int w = rem - h * W_;
    float acc[16];
    #pragma unroll
    for (int j = 0; j < 16; j++) acc[j] = b2[cog + j];
    for (int ci = 0; ci < 64; ci++) {
        float s1 = ws[WS_SC1 + ci];   // wave-uniform -> scalar load
        float s2 = ws[WS_SH1 + ci];
        const float* src = h1 + (b * 64 + ci) * HW;
        float v[9];
        #pragma unroll
        for (int dy = 0; dy < 3; dy++)
            #pragma unroll
            for (int dx = 0; dx < 3; dx++) {
                int hh = h + dy - 1, ww = w + dx - 1;
                float val = 0.f;
                if (hh >= 0 && hh < H_ && ww >= 0 && ww < W_)
                    val = fmaxf(fmaf(s1, src[hh * W_ + ww], s2), 0.f);
                v[dy * 3 + dx] = val;
            }
        const float* wrow = w2 + ci * 9;   // + co*576, wave-uniform addresses
        #pragma unroll
        for (int j = 0; j < 16; j++) {
            const float* wp = wrow + (cog + j) * 576;
            #pragma unroll
            for (int k = 0; k < 9; k++) acc[j] = fmaf(wp[k], v[k], acc[j]);
        }
    }
    #pragma unroll
    for (int j = 0; j < 16; j++)
        h2[(b * 64 + cog + j) * HW + rem] = acc[j];
}

// ---------------- BN2 + ReLU -> final bev output --------------------------
__global__ __launch_bounds__(256) void k_bnrelu(const float* __restrict__ h2,
                                                const float* __restrict__ ws,
                                                float* __restrict__ out) {
    int t = blockIdx.x * 256 + threadIdx.x;
    int f = t * 4;
    if (f >= BEVN) return;
    int c = (f / HW) & 63;
    float sc = ws[WS_SC2 + c], sh = ws[WS_SH2 + c];
    float4 v = *(const float4*)(h2 + f);
    v.x = fmaxf(fmaf(sc, v.x, sh), 0.f);
    v.y = fmaxf(fmaf(sc, v.y, sh), 0.f);
    v.z = fmaxf(fmaf(sc, v.z, sh), 0.f);
    v.w = fmaxf(fmaf(sc, v.w, sh), 0.f);
    *(float4*)(out + f) = v;
}

extern "C" void kernel_launch(void* const* d_in, const int* in_sizes, int n_in,
                              void* d_out, int out_size, void* d_ws, size_t ws_size,
                              hipStream_t stream) {
    // input order: image_features(0,unused), intrinsics(1), extrinsics(2,unused),
    // view_attention(3), depth_attention(4), c1w(5), c1b(6), bn1_g(7), bn1_b(8),
    // c2w(9), c2b(10), bn2_g(11), bn2_b(12), depths(13), xy1(14,computed inline)
    const float* K4     = (const float*)d_in[1];
    const float* vatt   = (const float*)d_in[3];
    const float* datt   = (const float*)d_in[4];
    const float* c1w    = (const float*)d_in[5];
    const float* c1b    = (const float*)d_in[6];
    const float* g1     = (const float*)d_in[7];
    const float* bb1    = (const float*)d_in[8];
    const float* c2w    = (const float*)d_in[9];
    const float* c2b    = (const float*)d_in[10];
    const float* g2     = (const float*)d_in[11];
    const float* bb2    = (const float*)d_in[12];
    const float* depths = (const float*)d_in[13];

    float* out  = (float*)d_out;
    float* ws   = (float*)d_ws;
    // scratch lives inside the pc region of d_out; k_pc overwrites it last
    float* h1   = out;                 // 5,767,168 floats
    float* h2   = out + BEVN;          // 5,767,168 floats
    float* bevf = out + 2 * BEVN;      // 270,336 floats
    float* bev  = out + PC_SIZE;       // final bev output

    k_prep<<<1, 256, 0, stream>>>(K4, datt, ws);
    k_bevf<<<BHW / 256, 256, 0, stream>>>(vatt, depths, ws, bevf);
    k_conv1<<<BHW / 256, 256, 0, stream>>>(bevf, c1w, c1b, h1);
    k_stats<<<512, 256, 0, stream>>>(h1, ws, WS_SUM1, WS_SQ1);
    k_fin<<<1, 64, 0, stream>>>(g1, bb1, ws, WS_SUM1, WS_SQ1, WS_SC1, WS_SH1);
    k_conv2<<<dim3(352, 4), 256, 0, stream>>>(h1, c2w, c2b, ws, h2);
    k_stats<<<512, 256, 0, stream>>>(h2, ws, WS_SUM2, WS_SQ2);
    k_fin<<<1, 64, 0, stream>>>(g2, bb2, ws, WS_SUM2, WS_SQ2, WS_SC2, WS_SH2);
    k_bnrelu<<<BEVN / 1024, 256, 0, stream>>>(h2, ws, bev);
    k_pc<<<(PC_SIZE / 4 + 255) / 256, 256, 0, stream>>>(depths, ws, out);
}

// Round 2
// 215.272 us; speedup vs baseline: 1.6627x; 1.6627x over previous
//
#include <hip/hip_runtime.h>

#define W_ 352
#define H_ 128
#define HW 45056
#define D_ 48
#define B_ 2
#define N_ 6
#define DHW (D_*HW)          // 2,162,688
#define PC_SIZE (36*DHW)     // 77,856,768  (B*N*3 * D*HW)
#define BHW (B_*HW)          // 90,112
#define BEVN (B_*64*HW)      // 5,767,168

// ws float offsets
#define WS_KINV 0     // 12*9 = 108
#define WS_DA   128   // 48
#define WS_SUM1 192
#define WS_SQ1  256
#define WS_SC1  320
#define WS_SH1  384
#define WS_SUM2 448
#define WS_SQ2  512
#define WS_SC2  576
#define WS_SH2  640

typedef __attribute__((ext_vector_type(8))) short bf16x8;
typedef __attribute__((ext_vector_type(4))) float f32x4;

static __device__ inline unsigned short f2bf(float f) {
    union { float f; unsigned u; } v; v.f = f;
    unsigned r = v.u + 0x7FFF + ((v.u >> 16) & 1);
    return (unsigned short)(r >> 16);
}

// ---------------- prep: 3x3 inverses, depth softmax, zero accumulators ----
__global__ void k_prep(const float* __restrict__ K4, const float* __restrict__ datt,
                       float* __restrict__ ws) {
    int t = threadIdx.x;
    for (int i = WS_SUM1 + t; i < WS_SC2 + 64; i += 256) ws[i] = 0.f;
    if (t < 12) {
        const float* M = K4 + t * 16;
        float a = M[0], b = M[1], c = M[2];
        float d = M[4], e = M[5], f = M[6];
        float g = M[8], h = M[9], ii = M[10];
        float det = a*(e*ii - f*h) - b*(d*ii - f*g) + c*(d*h - e*g);
        float inv = 1.f / det;
        float* o = ws + WS_KINV + t * 9;
        o[0] = (e*ii - f*h)*inv; o[1] = (c*h - b*ii)*inv; o[2] = (b*f - c*e)*inv;
        o[3] = (f*g - d*ii)*inv; o[4] = (a*ii - c*g)*inv; o[5] = (c*d - a*f)*inv;
        o[6] = (d*h - e*g)*inv;  o[7] = (b*g - a*h)*inv;  o[8] = (a*e - b*d)*inv;
    }
    if (t == 0) {
        float mx = -1e30f;
        for (int k = 0; k < D_; k++) mx = fmaxf(mx, datt[k]);
        float s = 0.f, e[D_];
        for (int k = 0; k < D_; k++) { e[k] = expf(datt[k] - mx); s += e[k]; }
        float invs = 1.f / s;
        for (int k = 0; k < D_; k++) ws[WS_DA + k] = e[k] * invs;
    }
}

// ---------------- pc writer (the big 311MB streaming store) ----------------
__global__ __launch_bounds__(256) void k_pc(const float* __restrict__ depths,
                                            const float* __restrict__ ws,
                                            float* __restrict__ out) {
    int t = blockIdx.x * 256 + threadIdx.x;
    int f = t * 4;
    if (f >= PC_SIZE) return;
    int bnc = f / DHW;
    int r1  = f - bnc * DHW;
    int d   = r1 / HW;
    int p   = r1 - d * HW;
    int y   = p / W_;
    int x   = p - y * W_;
    float ka = ws[WS_KINV + bnc*3 + 0];
    float kb = ws[WS_KINV + bnc*3 + 1];
    float kc = ws[WS_KINV + bnc*3 + 2];
    float dep = depths[d];
    float base = fmaf(kb, (float)y, kc);
    float4 v;
    v.x = dep * fmaf(ka, (float)(x + 0), base);
    v.y = dep * fmaf(ka, (float)(x + 1), base);
    v.z = dep * fmaf(ka, (float)(x + 2), base);
    v.w = dep * fmaf(ka, (float)(x + 3), base);
    *(float4*)(out + f) = v;
}

// ---------------- bev_features = einsum('bnchwd,d,nhw->bchw') --------------
__global__ __launch_bounds__(256) void k_bevf(const float* __restrict__ vatt,
                                              const float* __restrict__ depths,
                                              const float* __restrict__ ws,
                                              float* __restrict__ bevf) {
    int pix = blockIdx.x * 256 + threadIdx.x;
    int b = pix / HW;
    int rem = pix - b * HW;
    float v[N_]; float mx = -1e30f;
    for (int n = 0; n < N_; n++) { v[n] = vatt[n * HW + rem]; mx = fmaxf(mx, v[n]); }
    float s = 0.f;
    for (int n = 0; n < N_; n++) { v[n] = expf(v[n] - mx); s += v[n]; }
    float invs = 1.f / s;
    float acc0 = 0.f, acc1 = 0.f, acc2 = 0.f;
    int base = rem * D_;
    for (int n = 0; n < N_; n++) {
        float van = v[n] * invs;
        const float* kv = ws + WS_KINV + (b * N_ + n) * 9;
        float a0 = kv[0], a1 = kv[1], a2 = kv[2];
        float b0 = kv[3], b1 = kv[4], b2 = kv[5];
        float c0 = kv[6], c1 = kv[7], c2 = kv[8];
        for (int dd = 0; dd < D_; dd++) {
            int q = base + dd;
            int d = q / HW;
            int p = q - d * HW;
            int yy = p / W_;
            int xx = p - yy * W_;
            float wq = van * ws[WS_DA + dd] * depths[d];
            float fx = (float)xx, fy = (float)yy;
            acc0 += wq * fmaf(a0, fx, fmaf(a1, fy, a2));
            acc1 += wq * fmaf(b0, fx, fmaf(b1, fy, b2));
            acc2 += wq * fmaf(c0, fx, fmaf(c1, fy, c2));
        }
    }
    bevf[(b * 3 + 0) * HW + rem] = acc0;
    bevf[(b * 3 + 1) * HW + rem] = acc1;
    bevf[(b * 3 + 2) * HW + rem] = acc2;
}

// ---------------- conv1: 3 -> 64, 3x3 SAME -------------------------------
__global__ __launch_bounds__(256) void k_conv1(const float* __restrict__ bevf,
                                               const float* __restrict__ w1,
                                               const float* __restrict__ b1,
                                               float* __restrict__ h1) {
    __shared__ float wl[64 * 27];
    for (int i = threadIdx.x; i < 64 * 27; i += 256) wl[i] = w1[i];
    __syncthreads();
    int pix = blockIdx.x * 256 + threadIdx.x;
    int b = pix / HW;
    int rem = pix - b * HW;
    int h = rem / W_;
    int w = rem - h * W_;
    float v[27];
    #pragma unroll
    for (int ci = 0; ci < 3; ci++)
        #pragma unroll
        for (int dy = 0; dy < 3; dy++)
            #pragma unroll
            for (int dx = 0; dx < 3; dx++) {
                int hh = h + dy - 1, ww = w + dx - 1;
                float val = 0.f;
                if (hh >= 0 && hh < H_ && ww >= 0 && ww < W_)
                    val = bevf[(b * 3 + ci) * HW + hh * W_ + ww];
                v[ci * 9 + dy * 3 + dx] = val;
            }
    for (int co = 0; co < 64; co++) {
        float acc = b1[co];
        #pragma unroll
        for (int k = 0; k < 27; k++) acc = fmaf(wl[co * 27 + k], v[k], acc);
        h1[(b * 64 + co) * HW + rem] = acc;
    }
}

// ---------------- per-channel sum / sumsq (for BN training stats) ---------
__global__ __launch_bounds__(256) void k_stats(const float* __restrict__ x,
                                               float* __restrict__ ws,
                                               int sumOff, int sqOff) {
    int c = blockIdx.x >> 3;
    int slice = blockIdx.x & 7;
    float s = 0.f, sq = 0.f;
    int j0 = slice * 11264;
    for (int i = threadIdx.x; i < 11264; i += 256) {
        int j = j0 + i;
        int b = (j >= HW) ? 1 : 0;
        float val = x[(b * 64 + c) * HW + (j - b * HW)];
        s += val;
        sq = fmaf(val, val, sq);
    }
    __shared__ float ls[256], lq[256];
    ls[threadIdx.x] = s; lq[threadIdx.x] = sq;
    __syncthreads();
    for (int st = 128; st > 0; st >>= 1) {
        if (threadIdx.x < st) {
            ls[threadIdx.x] += ls[threadIdx.x + st];
            lq[threadIdx.x] += lq[threadIdx.x + st];
        }
        __syncthreads();
    }
    if (threadIdx.x == 0) {
        atomicAdd(ws + sumOff + c, ls[0]);
        atomicAdd(ws + sqOff + c, lq[0]);
    }
}

// ---------------- finalize BN scale/shift ---------------------------------
__global__ void k_fin(const float* __restrict__ g, const float* __restrict__ bb,
                      float* __restrict__ ws, int sumOff, int sqOff, int scOff, int shOff) {
    int c = threadIdx.x;
    if (c >= 64) return;
    const float invM = 1.f / (float)BHW;
    float m = ws[sumOff + c] * invM;
    float var = ws[sqOff + c] * invM - m * m;
    float sc = g[c] / sqrtf(var + 1e-5f);
    ws[scOff + c] = sc;
    ws[shOff + c] = bb[c] - m * sc;
}

// ---------------- conv2 via MFMA implicit GEMM (bf16) ---------------------
// Block: 32x4 output pixel tile (128 pixels) x 64 out-channels, batch = blockIdx.z.
// A tile: BN1+ReLU(h1) halo (6 rows x 34 cols) x 64 ch, bf16 in LDS, XOR-swizzled
// 16B slots. Per-tap 64x64 weight tile. 9 tap-GEMMs of K=64 accumulate in AGPRs.
__global__ __launch_bounds__(256) void k_conv2(const float* __restrict__ h1,
                                               const float* __restrict__ w2,
                                               const float* __restrict__ b2,
                                               const float* __restrict__ ws,
                                               float* __restrict__ h2) {
    __shared__ unsigned short sA[204 * 64];  // [haloPix r][64ch], 128B rows, swizzled
    __shared__ unsigned short sB[64 * 64];   // [co n][64ci], 128B rows, swizzled

    const int tid = threadIdx.x;
    const int b   = blockIdx.z;
    const int x0  = blockIdx.x * 32;
    const int y0  = blockIdx.y * 4;
    const float* h1b = h1 + b * 64 * HW;

    // ---- stage A: 204 halo pixels x 64 channels, BN1+ReLU fused, bf16 ----
    for (int idx = tid; idx < 204 * 64; idx += 256) {
        int ci = idx / 204;
        int r  = idx - ci * 204;
        int hy = r / 34;
        int hx = r - hy * 34;
        int py = y0 + hy - 1, px = x0 + hx - 1;
        float v = 0.f;
        if (py >= 0 && py < H_ && px >= 0 && px < W_) {
            float xv = h1b[ci * HW + py * W_ + px];
            v = fmaxf(fmaf(ws[WS_SC1 + ci], xv, ws[WS_SH1 + ci]), 0.f);
        }
        int slot = (ci >> 3) ^ (r & 7);
        sA[r * 64 + slot * 8 + (ci & 7)] = f2bf(v);
    }

    const int w    = tid >> 6;       // wave id = tile row ty
    const int lane = tid & 63;
    const int g    = lane >> 4;
    const int c16  = lane & 15;

    f32x4 acc[2][4];
    #pragma unroll
    for (int m = 0; m < 2; m++)
        #pragma unroll
        for (int n = 0; n < 4; n++)
            acc[m][n] = (f32x4){0.f, 0.f, 0.f, 0.f};

    for (int tap = 0; tap < 9; ++tap) {
        int dy = tap / 3, dx = tap - dy * 3;
        __syncthreads();   // A complete (iter 0) / prior-tap reads of sB done
        // ---- stage B: w2[:, :, dy, dx] as [n][k] bf16, swizzled ----
        for (int i = tid; i < 4096; i += 256) {
            int n = i >> 6, k = i & 63;
            float wv = w2[(n * 64 + k) * 9 + tap];
            int slot = (k >> 3) ^ (n & 7);
            sB[n * 64 + slot * 8 + (k & 7)] = f2bf(wv);
        }
        __syncthreads();

        // ---- A fragments: rows m = 16*mrep + c16 (pixels of tile-row w) ----
        bf16x8 afr[2][2];
        #pragma unroll
        for (int mrep = 0; mrep < 2; mrep++) {
            #pragma unroll
            for (int kk = 0; kk < 2; kk++) {
                int r = (w + dy) * 34 + dx + c16 + 16 * mrep;
                int slot = (g + 4 * kk) ^ (r & 7);
                afr[mrep][kk] = *(const bf16x8*)(&sA[r * 64 + slot * 8]);
            }
        }
        #pragma unroll
        for (int nrep = 0; nrep < 4; nrep++) {
            int n = 16 * nrep + c16;
            #pragma unroll
            for (int kk = 0; kk < 2; kk++) {
                int slot = (g + 4 * kk) ^ (n & 7);
                bf16x8 bfr = *(const bf16x8*)(&sB[n * 64 + slot * 8]);
                #pragma unroll
                for (int mrep = 0; mrep < 2; mrep++) {
                    acc[mrep][nrep] = __builtin_amdgcn_mfma_f32_16x16x32_bf16(
                        afr[mrep][kk], bfr, acc[mrep][nrep], 0, 0, 0);
                }
            }
        }
    }

    // ---- epilogue: bias + store fp32 ----
    const int y = y0 + w;
    #pragma unroll
    for (int nrep = 0; nrep < 4; nrep++) {
        int co = 16 * nrep + c16;
        float bias = b2[co];
        float* dst = h2 + (b * 64 + co) * HW + y * W_;
        #pragma unroll
        for (int mrep = 0; mrep < 2; mrep++) {
            #pragma unroll
            for (int j = 0; j < 4; j++) {
                int x = x0 + 16 * mrep + g * 4 + j;
                dst[x] = acc[mrep][nrep][j] + bias;
            }
        }
    }
}

// ---------------- BN2 + ReLU -> final bev output --------------------------
__global__ __launch_bounds__(256) void k_bnrelu(const float* __restrict__ h2,
                                                const float* __restrict__ ws,
                                                float* __restrict__ out) {
    int t = blockIdx.x * 256 + threadIdx.x;
    int f = t * 4;
    if (f >= BEVN) return;
    int c = (f / HW) & 63;
    float sc = ws[WS_SC2 + c], sh = ws[WS_SH2 + c];
    float4 v = *(const float4*)(h2 + f);
    v.x = fmaxf(fmaf(sc, v.x, sh), 0.f);
    v.y = fmaxf(fmaf(sc, v.y, sh), 0.f);
    v.z = fmaxf(fmaf(sc, v.z, sh), 0.f);
    v.w = fmaxf(fmaf(sc, v.w, sh), 0.f);
    *(float4*)(out + f) = v;
}

extern "C" void kernel_launch(void* const* d_in, const int* in_sizes, int n_in,
                              void* d_out, int out_size, void* d_ws, size_t ws_size,
                              hipStream_t stream) {
    const float* K4     = (const float*)d_in[1];
    const float* vatt   = (const float*)d_in[3];
    const float* datt   = (const float*)d_in[4];
    const float* c1w    = (const float*)d_in[5];
    const float* c1b    = (const float*)d_in[6];
    const float* g1     = (const float*)d_in[7];
    const float* bb1    = (const float*)d_in[8];
    const float* c2w    = (const float*)d_in[9];
    const float* c2b    = (const float*)d_in[10];
    const float* g2     = (const float*)d_in[11];
    const float* bb2    = (const float*)d_in[12];
    const float* depths = (const float*)d_in[13];

    float* out  = (float*)d_out;
    float* ws   = (float*)d_ws;
    float* h1   = out;                 // scratch inside pc region
    float* h2   = out + BEVN;
    float* bevf = out + 2 * BEVN;
    float* bev  = out + PC_SIZE;       // final bev output

    k_prep<<<1, 256, 0, stream>>>(K4, datt, ws);
    k_bevf<<<BHW / 256, 256, 0, stream>>>(vatt, depths, ws, bevf);
    k_conv1<<<BHW / 256, 256, 0, stream>>>(bevf, c1w, c1b, h1);
    k_stats<<<512, 256, 0, stream>>>(h1, ws, WS_SUM1, WS_SQ1);
    k_fin<<<1, 64, 0, stream>>>(g1, bb1, ws, WS_SUM1, WS_SQ1, WS_SC1, WS_SH1);
    k_conv2<<<dim3(11, 32, 2), 256, 0, stream>>>(h1, c2w, c2b, ws, h2);
    k_stats<<<512, 256, 0, stream>>>(h2, ws, WS_SUM2, WS_SQ2);
    k_fin<<<1, 64, 0, stream>>>(g2, bb2, ws, WS_SUM2, WS_SQ2, WS_SC2, WS_SH2);
    k_bnrelu<<<BEVN / 1024, 256, 0, stream>>>(h2, ws, bev);
    k_pc<<<(PC_SIZE / 4 + 255) / 256, 256, 0, stream>>>(depths, ws, out);
}

// Round 4
// 159.566 us; speedup vs baseline: 2.2432x; 1.3491x over previous
//
#include <hip/hip_runtime.h>

#define W_ 352
#define H_ 128
#define HW 45056
#define D_ 48
#define B_ 2
#define N_ 6
#define DHW (D_*HW)          // 2,162,688
#define PC_SIZE (36*DHW)     // 77,856,768  (B*N*3 * D*HW)
#define BHW (B_*HW)          // 90,112
#define BEVN (B_*64*HW)      // 5,767,168

// ws float offsets
#define WS_KINV 0     // 12*9 = 108
#define WS_DA   128   // 48
#define WS_SUM1 192
#define WS_SQ1  256
#define WS_SUM2 448
#define WS_SQ2  512

typedef unsigned short ushort_t;
typedef __attribute__((ext_vector_type(8))) short bf16x8;
typedef __attribute__((ext_vector_type(4))) float f32x4;
typedef __attribute__((ext_vector_type(8))) unsigned short u16x8;

static __device__ inline ushort_t f2bf(float f) {
    union { float f; unsigned u; } v; v.f = f;
    unsigned r = v.u + 0x7FFF + ((v.u >> 16) & 1);
    return (ushort_t)(r >> 16);
}
static __device__ inline float bf2f(ushort_t u) {
    union { unsigned u; float f; } v; v.u = ((unsigned)u) << 16; return v.f;
}

// ---- prep: Kinv, depth softmax, zero accumulators, weight prepack --------
__global__ void k_prep(const float* __restrict__ K4, const float* __restrict__ datt,
                       const float* __restrict__ w2, float* __restrict__ ws,
                       ushort_t* __restrict__ packedW) {
    int bid = blockIdx.x, t = threadIdx.x;
    if (bid == 0) {
        for (int i = WS_SUM1 + t; i < 640; i += 256) ws[i] = 0.f;
        if (t < 12) {
            const float* M = K4 + t * 16;
            float a = M[0], b = M[1], c = M[2];
            float d = M[4], e = M[5], f = M[6];
            float g = M[8], h = M[9], ii = M[10];
            float det = a*(e*ii - f*h) - b*(d*ii - f*g) + c*(d*h - e*g);
            float inv = 1.f / det;
            float* o = ws + WS_KINV + t * 9;
            o[0] = (e*ii - f*h)*inv; o[1] = (c*h - b*ii)*inv; o[2] = (b*f - c*e)*inv;
            o[3] = (f*g - d*ii)*inv; o[4] = (a*ii - c*g)*inv; o[5] = (c*d - a*f)*inv;
            o[6] = (d*h - e*g)*inv;  o[7] = (b*g - a*h)*inv;  o[8] = (a*e - b*d)*inv;
        }
        if (t == 0) {
            float mx = -1e30f;
            for (int k = 0; k < D_; k++) mx = fmaxf(mx, datt[k]);
            float s = 0.f, e[D_];
            for (int k = 0; k < D_; k++) { e[k] = expf(datt[k] - mx); s += e[k]; }
            float invs = 1.f / s;
            for (int k = 0; k < D_; k++) ws[WS_DA + k] = e[k] * invs;
        }
    } else {
        int e = (bid - 1) * 256 + t;        // 0..36863
        int tap = e >> 12;                  // e/4096
        int r   = e & 4095;
        int n   = r >> 6, k = r & 63;
        int slot = (k >> 3) ^ (n & 7);
        packedW[tap * 4096 + n * 64 + slot * 8 + (k & 7)] = f2bf(w2[(n * 64 + k) * 9 + tap]);
    }
}

// ---- pc writer (311MB streaming store) -----------------------------------
__global__ __launch_bounds__(256) void k_pc(const float* __restrict__ depths,
                                            const float* __restrict__ ws,
                                            float* __restrict__ out) {
    int t = blockIdx.x * 256 + threadIdx.x;
    int f = t * 4;
    int bnc = f / DHW;
    int r1  = f - bnc * DHW;
    int d   = r1 / HW;
    int p   = r1 - d * HW;
    int y   = p / W_;
    int x   = p - y * W_;
    float ka = ws[WS_KINV + bnc*3 + 0];
    float kb = ws[WS_KINV + bnc*3 + 1];
    float kc = ws[WS_KINV + bnc*3 + 2];
    float dep = depths[d];
    float base = fmaf(kb, (float)y, kc);
    f32x4 v;
    v.x = dep * fmaf(ka, (float)(x + 0), base);
    v.y = dep * fmaf(ka, (float)(x + 1), base);
    v.z = dep * fmaf(ka, (float)(x + 2), base);
    v.w = dep * fmaf(ka, (float)(x + 3), base);
    __builtin_nontemporal_store(v, (f32x4*)(out + f));
}

// ---- bev_features: factorized einsum -------------------------------------
// bev[b,c,pix] = sum_n va[n,pix] * (Kinv[b,n,c,:] . (S0,S1,S2)),
// S = sum_dd da[dd]*depths[d(q)]*(x(q), y(q), 1), q = pix*48+dd (scrambled reshape)
__global__ __launch_bounds__(256) void k_bevf(const float* __restrict__ vatt,
                                              const float* __restrict__ depths,
                                              const float* __restrict__ ws,
                                              float* __restrict__ bevf) {
    __shared__ float sDep[48], sDa[48];
    int tid = threadIdx.x;
    if (tid < 48) { sDep[tid] = depths[tid]; sDa[tid] = ws[WS_DA + tid]; }
    __syncthreads();
    int pix = blockIdx.x * 256 + tid;
    float va[N_]; float mx = -1e30f;
    for (int n = 0; n < N_; n++) { va[n] = vatt[n * HW + pix]; mx = fmaxf(mx, va[n]); }
    float s = 0.f;
    for (int n = 0; n < N_; n++) { va[n] = expf(va[n] - mx); s += va[n]; }
    float invs = 1.f / s;
    int q0 = pix * 48;
    int d = q0 / HW;
    int p = q0 - d * HW;
    int y = p / W_;
    int x = p - y * W_;
    float fx = (float)x, fy = (float)y;
    float S0 = 0.f, S1 = 0.f, S2 = 0.f;
    #pragma unroll
    for (int dd = 0; dd < D_; dd++) {
        float wq = sDa[dd] * sDep[d];
        S0 = fmaf(wq, fx, S0);
        S1 = fmaf(wq, fy, S1);
        S2 += wq;
        x++; fx += 1.f;
        if (x == W_) { x = 0; fx = 0.f; y++; fy += 1.f; if (y == H_) { y = 0; fy = 0.f; d++; } }
    }
    for (int b = 0; b < B_; b++) {
        float a0 = 0.f, a1 = 0.f, a2 = 0.f;
        for (int n = 0; n < N_; n++) {
            float van = va[n] * invs;
            const float* kv = ws + WS_KINV + (b * N_ + n) * 9;
            a0 = fmaf(van, fmaf(kv[0], S0, fmaf(kv[1], S1, kv[2] * S2)), a0);
            a1 = fmaf(van, fmaf(kv[3], S0, fmaf(kv[4], S1, kv[5] * S2)), a1);
            a2 = fmaf(van, fmaf(kv[6], S0, fmaf(kv[7], S1, kv[8] * S2)), a2);
        }
        bevf[(b * 3 + 0) * HW + pix] = a0;
        bevf[(b * 3 + 1) * HW + pix] = a1;
        bevf[(b * 3 + 2) * HW + pix] = a2;
    }
}

// ---- conv1: 3 -> 64, 3x3 SAME, bf16 out ----------------------------------
__global__ __launch_bounds__(256) void k_conv1(const float* __restrict__ bevf,
                                               const float* __restrict__ w1,
                                               const float* __restrict__ b1,
                                               ushort_t* __restrict__ h1b) {
    __shared__ float wl[64 * 27];
    for (int i = threadIdx.x; i < 64 * 27; i += 256) wl[i] = w1[i];
    __syncthreads();
    int pix = blockIdx.x * 256 + threadIdx.x;
    int b = pix / HW;
    int rem = pix - b * HW;
    int h = rem / W_;
    int w = rem - h * W_;
    float v[27];
    #pragma unroll
    for (int ci = 0; ci < 3; ci++)
        #pragma unroll
        for (int dy = 0; dy < 3; dy++)
            #pragma unroll
            for (int dx = 0; dx < 3; dx++) {
                int hh = h + dy - 1, ww = w + dx - 1;
                float val = 0.f;
                if (hh >= 0 && hh < H_ && ww >= 0 && ww < W_)
                    val = bevf[(b * 3 + ci) * HW + hh * W_ + ww];
                v[ci * 9 + dy * 3 + dx] = val;
            }
    for (int co = 0; co < 64; co++) {
        float acc = b1[co];
        #pragma unroll
        for (int k = 0; k < 27; k++) acc = fmaf(wl[co * 27 + k], v[k], acc);
        h1b[(b * 64 + co) * HW + rem] = f2bf(acc);
    }
}

// ---- per-channel sum/sumsq on bf16 tensor --------------------------------
__global__ __launch_bounds__(256) void k_stats(const ushort_t* __restrict__ x,
                                               float* __restrict__ ws,
                                               int sumOff, int sqOff) {
    int c = blockIdx.x >> 3;
    int slice = blockIdx.x & 7;
    float s = 0.f, sq = 0.f;
    int j0 = slice * 11264;
    for (int i = threadIdx.x; i < 11264; i += 256) {
        int j = j0 + i;
        int b = (j >= HW) ? 1 : 0;
        float val = bf2f(x[(b * 64 + c) * HW + (j - b * HW)]);
        s += val;
        sq = fmaf(val, val, sq);
    }
    __shared__ float ls[256], lq[256];
    ls[threadIdx.x] = s; lq[threadIdx.x] = sq;
    __syncthreads();
    for (int st = 128; st > 0; st >>= 1) {
        if (threadIdx.x < st) {
            ls[threadIdx.x] += ls[threadIdx.x + st];
            lq[threadIdx.x] += lq[threadIdx.x + st];
        }
        __syncthreads();
    }
    if (threadIdx.x == 0) {
        atomicAdd(ws + sumOff + c, ls[0]);
        atomicAdd(ws + sqOff + c, lq[0]);
    }
}

// ---- conv2 via MFMA implicit GEMM; BN1 fin+apply fused in, BN2 stats out -
__global__ __launch_bounds__(256) void k_conv2(const ushort_t* __restrict__ h1b,
                                               const ushort_t* __restrict__ packedW,
                                               const float* __restrict__ b2,
                                               const float* __restrict__ g1,
                                               const float* __restrict__ bb1,
                                               float* __restrict__ ws,
                                               ushort_t* __restrict__ h2b) {
    __shared__ __align__(16) ushort_t sA[204 * 64];
    __shared__ __align__(16) ushort_t sB[3 * 4096];
    __shared__ float sSc[64], sSh[64];
    __shared__ float sRs[4][64], sRq[4][64];

    const int tid = threadIdx.x;
    // inline BN1 finalize
    if (tid < 64) {
        const float invM = 1.f / (float)BHW;
        float m = ws[WS_SUM1 + tid] * invM;
        float var = ws[WS_SQ1 + tid] * invM - m * m;
        float sc = g1[tid] * rsqrtf(var + 1e-5f);
        sSc[tid] = sc;
        sSh[tid] = bb1[tid] - m * sc;
    }
    __syncthreads();

    const int b  = blockIdx.z;
    const int x0 = blockIdx.x * 32;
    const int y0 = blockIdx.y * 4;
    const ushort_t* h1p = h1b + b * 64 * HW;

    // stage A: 204 halo pixels x 64ch, BN1+ReLU, swizzled bf16
    for (int idx = tid; idx < 204 * 64; idx += 256) {
        int ci = idx / 204;
        int r  = idx - ci * 204;
        int hy = r / 34;
        int hx = r - hy * 34;
        int py = y0 + hy - 1, px = x0 + hx - 1;
        float v = 0.f;
        if ((unsigned)py < H_ && (unsigned)px < W_)
            v = fmaxf(fmaf(sSc[ci], bf2f(h1p[ci * HW + py * W_ + px]), sSh[ci]), 0.f);
        int slot = (ci >> 3) ^ (r & 7);
        sA[r * 64 + slot * 8 + (ci & 7)] = f2bf(v);
    }

    const int w    = tid >> 6;
    const int lane = tid & 63;
    const int g    = lane >> 4;
    const int c16  = lane & 15;

    f32x4 acc[2][4];
    #pragma unroll
    for (int m = 0; m < 2; m++)
        #pragma unroll
        for (int n = 0; n < 4; n++)
            acc[m][n] = (f32x4){0.f, 0.f, 0.f, 0.f};

    for (int grp = 0; grp < 3; grp++) {      // grp == dy
        __syncthreads();   // prior-group sB reads done (iter0: join A-stage too)
        const uint4* src = (const uint4*)(packedW + grp * 3 * 4096);
        uint4* dst = (uint4*)sB;
        #pragma unroll
        for (int i = 0; i < 6; i++) dst[tid + 256 * i] = src[tid + 256 * i];
        __syncthreads();
        #pragma unroll
        for (int tt = 0; tt < 3; tt++) {     // tt == dx
            bf16x8 afr[2][2];
            #pragma unroll
            for (int mrep = 0; mrep < 2; mrep++)
                #pragma unroll
                for (int kk = 0; kk < 2; kk++) {
                    int r = (w + grp) * 34 + tt + c16 + 16 * mrep;
                    int slot = (g + 4 * kk) ^ (r & 7);
                    afr[mrep][kk] = *(const bf16x8*)(&sA[r * 64 + slot * 8]);
                }
            #pragma unroll
            for (int nrep = 0; nrep < 4; nrep++) {
                int n = 16 * nrep + c16;
                #pragma unroll
                for (int kk = 0; kk < 2; kk++) {
                    int slot = (g + 4 * kk) ^ (n & 7);
                    bf16x8 bfr = *(const bf16x8*)(&sB[tt * 4096 + n * 64 + slot * 8]);
                    #pragma unroll
                    for (int mrep = 0; mrep < 2; mrep++)
                        acc[mrep][nrep] = __builtin_amdgcn_mfma_f32_16x16x32_bf16(
                            afr[mrep][kk], bfr, acc[mrep][nrep], 0, 0, 0);
                }
            }
        }
    }

    // epilogue: bias, bf16 store, fused BN2 partial stats
    const int y = y0 + w;
    #pragma unroll
    for (int nrep = 0; nrep < 4; nrep++) {
        int co = 16 * nrep + c16;
        float bias = b2[co];
        ushort_t* dstrow = h2b + (b * 64 + co) * HW + y * W_;
        float s = 0.f, q = 0.f;
        #pragma unroll
        for (int mrep = 0; mrep < 2; mrep++)
            #pragma unroll
            for (int j = 0; j < 4; j++) {
                float val = acc[mrep][nrep][j] + bias;
                s += val;
                q = fmaf(val, val, q);
                dstrow[x0 + 16 * mrep + g * 4 + j] = f2bf(val);
            }
        s += __shfl_xor(s, 16); s += __shfl_xor(s, 32);
        q += __shfl_xor(q, 16); q += __shfl_xor(q, 32);
        if (g == 0) { sRs[w][co] = s; sRq[w][co] = q; }
    }
    __syncthreads();
    if (tid < 64) {
        float s = sRs[0][tid] + sRs[1][tid] + sRs[2][tid] + sRs[3][tid];
        float q = sRq[0][tid] + sRq[1][tid] + sRq[2][tid] + sRq[3][tid];
        atomicAdd(ws + WS_SUM2 + tid, s);
        atomicAdd(ws + WS_SQ2 + tid, q);
    }
}

// ---- BN2 finalize (inline) + ReLU -> final bev output --------------------
__global__ __launch_bounds__(256) void k_bnrelu(const ushort_t* __restrict__ h2b,
                                                const float* __restrict__ ws,
                                                const float* __restrict__ g2,
                                                const float* __restrict__ bb2,
                                                float* __restrict__ out) {
    int t = blockIdx.x * 256 + threadIdx.x;
    int f = t * 8;
    int c = (f / HW) & 63;
    const float invM = 1.f / (float)BHW;
    float m = ws[WS_SUM2 + c] * invM;
    float var = ws[WS_SQ2 + c] * invM - m * m;
    float sc = g2[c] * rsqrtf(var + 1e-5f);
    float sh = bb2[c] - m * sc;
    u16x8 v = *(const u16x8*)(h2b + f);
    f32x4 o0, o1;
    o0.x = fmaxf(fmaf(sc, bf2f(v[0]), sh), 0.f);
    o0.y = fmaxf(fmaf(sc, bf2f(v[1]), sh), 0.f);
    o0.z = fmaxf(fmaf(sc, bf2f(v[2]), sh), 0.f);
    o0.w = fmaxf(fmaf(sc, bf2f(v[3]), sh), 0.f);
    o1.x = fmaxf(fmaf(sc, bf2f(v[4]), sh), 0.f);
    o1.y = fmaxf(fmaf(sc, bf2f(v[5]), sh), 0.f);
    o1.z = fmaxf(fmaf(sc, bf2f(v[6]), sh), 0.f);
    o1.w = fmaxf(fmaf(sc, bf2f(v[7]), sh), 0.f);
    *(f32x4*)(out + f) = o0;
    *(f32x4*)(out + f + 4) = o1;
}

extern "C" void kernel_launch(void* const* d_in, const int* in_sizes, int n_in,
                              void* d_out, int out_size, void* d_ws, size_t ws_size,
                              hipStream_t stream) {
    const float* K4     = (const float*)d_in[1];
    const float* vatt   = (const float*)d_in[3];
    const float* datt   = (const float*)d_in[4];
    const float* c1w    = (const float*)d_in[5];
    const float* c1b    = (const float*)d_in[6];
    const float* g1     = (const float*)d_in[7];
    const float* bb1    = (const float*)d_in[8];
    const float* c2w    = (const float*)d_in[9];
    const float* c2b    = (const float*)d_in[10];
    const float* g2     = (const float*)d_in[11];
    const float* bb2    = (const float*)d_in[12];
    const float* depths = (const float*)d_in[13];

    float* out = (float*)d_out;
    float* ws  = (float*)d_ws;
    char* base = (char*)d_out;
    // scratch inside pc region of d_out (k_pc overwrites it last)
    ushort_t* h1b     = (ushort_t*)base;                        // 11.5 MB
    ushort_t* h2b     = (ushort_t*)(base + (16u << 20));        // 11.5 MB
    float*    bevf    = (float*)(base + (32u << 20));           // 1.1 MB
    ushort_t* packedW = (ushort_t*)(base + (36u << 20));        // 72 KB
    float*    bev     = out + PC_SIZE;                          // final bev

    k_prep<<<145, 256, 0, stream>>>(K4, datt, c2w, ws, packedW);
    k_bevf<<<HW / 256, 256, 0, stream>>>(vatt, depths, ws, bevf);
    k_conv1<<<BHW / 256, 256, 0, stream>>>(bevf, c1w, c1b, h1b);
    k_stats<<<512, 256, 0, stream>>>(h1b, ws, WS_SUM1, WS_SQ1);
    k_conv2<<<dim3(11, 32, 2), 256, 0, stream>>>(h1b, packedW, c2b, g1, bb1, ws, h2b);
    k_bnrelu<<<BEVN / 2048, 256, 0, stream>>>(h2b, ws, g2, bb2, bev);
    k_pc<<<PC_SIZE / 1024, 256, 0, stream>>>(depths, ws, out);
}

// Round 5
// 129.869 us; speedup vs baseline: 2.7561x; 1.2287x over previous
//
#include <hip/hip_runtime.h>

#define W_ 352
#define H_ 128
#define HW 45056
#define D_ 48
#define B_ 2
#define N_ 6
#define DHW (D_*HW)          // 2,162,688
#define PC_SIZE (36*DHW)     // 77,856,768
#define BHW (B_*HW)          // 90,112
#define BEVN (B_*64*HW)      // 5,767,168

#define WS_KINV 0     // 12*9
#define WS_SUM1 192
#define WS_SQ1  256
#define WS_SUM2 448
#define WS_SQ2  512

#define NBN_BLK (BEVN/2048)     // 2816
#define NPC_BLK (PC_SIZE/1024)  // 76032

typedef unsigned short ushort_t;
typedef __attribute__((ext_vector_type(8))) short bf16x8;
typedef __attribute__((ext_vector_type(4))) float f32x4;
typedef __attribute__((ext_vector_type(8))) unsigned short u16x8;

static __device__ inline ushort_t f2bf(float f) {
    union { float f; unsigned u; } v; v.f = f;
    unsigned r = v.u + 0x7FFF + ((v.u >> 16) & 1);
    return (ushort_t)(r >> 16);
}
static __device__ inline float bf2f(ushort_t u) {
    union { unsigned u; float f; } v; v.u = ((unsigned)u) << 16; return v.f;
}
static __device__ inline void invert3x3(const float* __restrict__ M, float* __restrict__ o) {
    float a = M[0], b = M[1], c = M[2];
    float d = M[4], e = M[5], f = M[6];
    float g = M[8], h = M[9], ii = M[10];
    float det = a*(e*ii - f*h) - b*(d*ii - f*g) + c*(d*h - e*g);
    float inv = 1.f / det;
    o[0] = (e*ii - f*h)*inv; o[1] = (c*h - b*ii)*inv; o[2] = (b*f - c*e)*inv;
    o[3] = (f*g - d*ii)*inv; o[4] = (a*ii - c*g)*inv; o[5] = (c*d - a*f)*inv;
    o[6] = (d*h - e*g)*inv;  o[7] = (b*g - a*h)*inv;  o[8] = (a*e - b*d)*inv;
}

// ---- K1: bev_features (per-block local Kinv/da); block 176 = ws prep -----
__global__ __launch_bounds__(256) void k_bevf(const float* __restrict__ K4,
                                              const float* __restrict__ datt,
                                              const float* __restrict__ vatt,
                                              const float* __restrict__ depths,
                                              float* __restrict__ ws,
                                              float* __restrict__ bevf) {
    int t = threadIdx.x;
    if (blockIdx.x == 176) {   // prep: publish Kinv for k_tail, zero stat accums
        for (int i = 192 + t; i < 640; i += 256) ws[i] = 0.f;
        if (t < 12) invert3x3(K4 + t * 16, ws + WS_KINV + t * 9);
        return;
    }
    __shared__ float sKinv[108], sDa[48], sDep[48];
    if (t < 48) sDep[t] = depths[t];
    if (t >= 192 && t < 204) invert3x3(K4 + (t - 192) * 16, sKinv + (t - 192) * 9);
    if (t == 255) {
        float mx = -1e30f;
        for (int k = 0; k < D_; k++) mx = fmaxf(mx, datt[k]);
        float s = 0.f, e[D_];
        for (int k = 0; k < D_; k++) { e[k] = expf(datt[k] - mx); s += e[k]; }
        float invs = 1.f / s;
        for (int k = 0; k < D_; k++) sDa[k] = e[k] * invs;
    }
    __syncthreads();
    int pix = blockIdx.x * 256 + t;   // [0, HW)
    float va[N_]; float mx = -1e30f;
    for (int n = 0; n < N_; n++) { va[n] = vatt[n * HW + pix]; mx = fmaxf(mx, va[n]); }
    float s = 0.f;
    for (int n = 0; n < N_; n++) { va[n] = expf(va[n] - mx); s += va[n]; }
    float invs = 1.f / s;
    int q0 = pix * 48;
    int d = q0 / HW;
    int p = q0 - d * HW;
    int y = p / W_;
    int x = p - y * W_;
    float fx = (float)x, fy = (float)y;
    float S0 = 0.f, S1 = 0.f, S2 = 0.f;
    #pragma unroll
    for (int dd = 0; dd < D_; dd++) {
        float wq = sDa[dd] * sDep[d];
        S0 = fmaf(wq, fx, S0);
        S1 = fmaf(wq, fy, S1);
        S2 += wq;
        x++; fx += 1.f;
        if (x == W_) { x = 0; fx = 0.f; y++; fy += 1.f; if (y == H_) { y = 0; fy = 0.f; d++; } }
    }
    for (int b = 0; b < B_; b++) {
        float a0 = 0.f, a1 = 0.f, a2 = 0.f;
        for (int n = 0; n < N_; n++) {
            float van = va[n] * invs;
            const float* kv = sKinv + (b * N_ + n) * 9;
            a0 = fmaf(van, fmaf(kv[0], S0, fmaf(kv[1], S1, kv[2] * S2)), a0);
            a1 = fmaf(van, fmaf(kv[3], S0, fmaf(kv[4], S1, kv[5] * S2)), a1);
            a2 = fmaf(van, fmaf(kv[6], S0, fmaf(kv[7], S1, kv[8] * S2)), a2);
        }
        bevf[(b * 3 + 0) * HW + pix] = a0;
        bevf[(b * 3 + 1) * HW + pix] = a1;
        bevf[(b * 3 + 2) * HW + pix] = a2;
    }
}

// ---- K2: conv1 (3->64), pixel-major bf16 out; blocks >=352 prepack w2 ----
__global__ __launch_bounds__(256) void k_conv1(const float* __restrict__ bevf,
                                               const float* __restrict__ w1,
                                               const float* __restrict__ b1,
                                               const float* __restrict__ w2,
                                               ushort_t* __restrict__ h1pm,
                                               ushort_t* __restrict__ packedW) {
    if (blockIdx.x >= 352) {   // weight prepack for conv2
        int e = (blockIdx.x - 352) * 256 + threadIdx.x;   // [0, 36864)
        int tap = e >> 12;
        int r   = e & 4095;
        int n   = r >> 6, k = r & 63;
        int slot = (k >> 3) ^ (n & 7);
        packedW[tap * 4096 + n * 64 + slot * 8 + (k & 7)] = f2bf(w2[(n * 64 + k) * 9 + tap]);
        return;
    }
    __shared__ float wl[64 * 27];
    for (int i = threadIdx.x; i < 64 * 27; i += 256) wl[i] = w1[i];
    __syncthreads();
    int pix = blockIdx.x * 256 + threadIdx.x;   // [0, BHW)
    int b = pix / HW;
    int rem = pix - b * HW;
    int h = rem / W_;
    int w = rem - h * W_;
    float v[27];
    #pragma unroll
    for (int ci = 0; ci < 3; ci++)
        #pragma unroll
        for (int dy = 0; dy < 3; dy++)
            #pragma unroll
            for (int dx = 0; dx < 3; dx++) {
                int hh = h + dy - 1, ww = w + dx - 1;
                float val = 0.f;
                if (hh >= 0 && hh < H_ && ww >= 0 && ww < W_)
                    val = bevf[(b * 3 + ci) * HW + hh * W_ + ww];
                v[ci * 9 + dy * 3 + dx] = val;
            }
    u16x8 pack[8];
    #pragma unroll
    for (int co = 0; co < 64; co++) {
        float acc = b1[co];
        #pragma unroll
        for (int k = 0; k < 27; k++) acc = fmaf(wl[co * 27 + k], v[k], acc);
        pack[co >> 3][co & 7] = (short)f2bf(acc);
    }
    ushort_t* dst = h1pm + pix * 64;
    #pragma unroll
    for (int j = 0; j < 8; j++)
        *(u16x8*)(dst + j * 8) = pack[j];
}

// ---- K3: BN1 stats on pixel-major bf16 (coalesced + shfl pre-reduce) -----
__global__ __launch_bounds__(256) void k_stats(const ushort_t* __restrict__ x,
                                               float* __restrict__ ws) {
    __shared__ float sSum[64], sSq[64];
    int tid = threadIdx.x;
    if (tid < 64) { sSum[tid] = 0.f; sSq[tid] = 0.f; }
    __syncthreads();
    int c8 = tid & 7;
    int lp = tid >> 3;           // 0..31
    int base = blockIdx.x * 352; // 256 blocks x 352 pixels = BHW
    float s[8] = {0,0,0,0,0,0,0,0}, q[8] = {0,0,0,0,0,0,0,0};
    for (int p = lp; p < 352; p += 32) {
        u16x8 v = *(const u16x8*)(x + (base + p) * 64 + c8 * 8);
        #pragma unroll
        for (int e = 0; e < 8; e++) {
            float f = bf2f(v[e]);
            s[e] += f;
            q[e] = fmaf(f, f, q[e]);
        }
    }
    #pragma unroll
    for (int e = 0; e < 8; e++) {
        s[e] += __shfl_xor(s[e], 8);  s[e] += __shfl_xor(s[e], 16); s[e] += __shfl_xor(s[e], 32);
        q[e] += __shfl_xor(q[e], 8);  q[e] += __shfl_xor(q[e], 16); q[e] += __shfl_xor(q[e], 32);
    }
    if ((tid & 56) == 0) {
        #pragma unroll
        for (int e = 0; e < 8; e++) {
            atomicAdd(&sSum[c8 * 8 + e], s[e]);
            atomicAdd(&sSq[c8 * 8 + e], q[e]);
        }
    }
    __syncthreads();
    if (tid < 64) {
        atomicAdd(ws + WS_SUM1 + tid, sSum[tid]);
        atomicAdd(ws + WS_SQ1 + tid, sSq[tid]);
    }
}

// ---- K4: conv2 MFMA implicit GEMM; BN1 fused in, fp32 out to bev region,
//          BN2 partial stats fused out ------------------------------------
__global__ __launch_bounds__(256) void k_conv2(const ushort_t* __restrict__ h1pm,
                                               const ushort_t* __restrict__ packedW,
                                               const float* __restrict__ b2,
                                               const float* __restrict__ g1,
                                               const float* __restrict__ bb1,
                                               float* __restrict__ ws,
                                               float* __restrict__ h2f) {
    __shared__ __align__(16) ushort_t sA[204 * 64];
    __shared__ __align__(16) ushort_t sB[3 * 4096];
    __shared__ float sSc[64], sSh[64];
    __shared__ float sRs[4][64], sRq[4][64];

    const int tid = threadIdx.x;
    if (tid < 64) {   // BN1 finalize
        const float invM = 1.f / (float)BHW;
        float m = ws[WS_SUM1 + tid] * invM;
        float var = ws[WS_SQ1 + tid] * invM - m * m;
        float sc = g1[tid] * rsqrtf(var + 1e-5f);
        sSc[tid] = sc;
        sSh[tid] = bb1[tid] - m * sc;
    }
    __syncthreads();

    const int b  = blockIdx.z;
    const int x0 = blockIdx.x * 32;
    const int y0 = blockIdx.y * 4;
    const ushort_t* h1p = h1pm + b * HW * 64;

    // stage A: 204 halo pixels x 64ch in u16x8 chunks, BN1+ReLU, swizzled
    for (int idx = tid; idx < 204 * 8; idx += 256) {
        int r  = idx >> 3;
        int c8 = idx & 7;
        int hy = r / 34;
        int hx = r - hy * 34;
        int py = y0 + hy - 1, px = x0 + hx - 1;
        u16x8 ov = {0, 0, 0, 0, 0, 0, 0, 0};
        if ((unsigned)py < H_ && (unsigned)px < W_) {
            u16x8 v = *(const u16x8*)(h1p + (py * W_ + px) * 64 + c8 * 8);
            #pragma unroll
            for (int e = 0; e < 8; e++) {
                int ci = c8 * 8 + e;
                float f = fmaxf(fmaf(sSc[ci], bf2f(v[e]), sSh[ci]), 0.f);
                ov[e] = (short)f2bf(f);
            }
        }
        int slot = c8 ^ (r & 7);
        *(u16x8*)(&sA[r * 64 + slot * 8]) = ov;
    }

    const int w    = tid >> 6;
    const int lane = tid & 63;
    const int g    = lane >> 4;
    const int c16  = lane & 15;

    f32x4 acc[2][4];
    #pragma unroll
    for (int m = 0; m < 2; m++)
        #pragma unroll
        for (int n = 0; n < 4; n++)
            acc[m][n] = (f32x4){0.f, 0.f, 0.f, 0.f};

    for (int grp = 0; grp < 3; grp++) {      // grp == dy
        __syncthreads();
        const uint4* src = (const uint4*)(packedW + grp * 3 * 4096);
        uint4* dst = (uint4*)sB;
        #pragma unroll
        for (int i = 0; i < 6; i++) dst[tid + 256 * i] = src[tid + 256 * i];
        __syncthreads();
        #pragma unroll
        for (int tt = 0; tt < 3; tt++) {     // tt == dx
            bf16x8 afr[2][2];
            #pragma unroll
            for (int mrep = 0; mrep < 2; mrep++)
                #pragma unroll
                for (int kk = 0; kk < 2; kk++) {
                    int r = (w + grp) * 34 + tt + c16 + 16 * mrep;
                    int slot = (g + 4 * kk) ^ (r & 7);
                    afr[mrep][kk] = *(const bf16x8*)(&sA[r * 64 + slot * 8]);
                }
            #pragma unroll
            for (int nrep = 0; nrep < 4; nrep++) {
                int n = 16 * nrep + c16;
                #pragma unroll
                for (int kk = 0; kk < 2; kk++) {
                    int slot = (g + 4 * kk) ^ (n & 7);
                    bf16x8 bfr = *(const bf16x8*)(&sB[tt * 4096 + n * 64 + slot * 8]);
                    #pragma unroll
                    for (int mrep = 0; mrep < 2; mrep++)
                        acc[mrep][nrep] = __builtin_amdgcn_mfma_f32_16x16x32_bf16(
                            afr[mrep][kk], bfr, acc[mrep][nrep], 0, 0, 0);
                }
            }
        }
    }

    // epilogue: bias, fp32 store to bev region (channel-major), BN2 stats
    const int y = y0 + w;
    #pragma unroll
    for (int nrep = 0; nrep < 4; nrep++) {
        int co = 16 * nrep + c16;
        float bias = b2[co];
        float* dstrow = h2f + (b * 64 + co) * HW + y * W_;
        float s = 0.f, q = 0.f;
        #pragma unroll
        for (int mrep = 0; mrep < 2; mrep++)
            #pragma unroll
            for (int j = 0; j < 4; j++) {
                float val = acc[mrep][nrep][j] + bias;
                s += val;
                q = fmaf(val, val, q);
                dstrow[x0 + 16 * mrep + g * 4 + j] = val;
            }
        s += __shfl_xor(s, 16); s += __shfl_xor(s, 32);
        q += __shfl_xor(q, 16); q += __shfl_xor(q, 32);
        if (g == 0) { sRs[w][co] = s; sRq[w][co] = q; }
    }
    __syncthreads();
    if (tid < 64) {
        float s = sRs[0][tid] + sRs[1][tid] + sRs[2][tid] + sRs[3][tid];
        float q = sRq[0][tid] + sRq[1][tid] + sRq[2][tid] + sRq[3][tid];
        atomicAdd(ws + WS_SUM2 + tid, s);
        atomicAdd(ws + WS_SQ2 + tid, q);
    }
}

// ---- K5: tail = BN2+ReLU in-place on bev  +  pc streaming writes ---------
__global__ __launch_bounds__(256) void k_tail(const float* __restrict__ depths,
                                              const float* __restrict__ ws,
                                              const float* __restrict__ g2,
                                              const float* __restrict__ bb2,
                                              float* __restrict__ out) {
    int bid = blockIdx.x;
    if (bid < NBN_BLK) {
        float* bev = out + PC_SIZE;
        int t = bid * 256 + threadIdx.x;
        int f = t * 8;
        int c = (f / HW) & 63;
        const float invM = 1.f / (float)BHW;
        float m = ws[WS_SUM2 + c] * invM;
        float var = ws[WS_SQ2 + c] * invM - m * m;
        float sc = g2[c] * rsqrtf(var + 1e-5f);
        float sh = bb2[c] - m * sc;
        f32x4 a = *(f32x4*)(bev + f);
        f32x4 d = *(f32x4*)(bev + f + 4);
        a.x = fmaxf(fmaf(sc, a.x, sh), 0.f);
        a.y = fmaxf(fmaf(sc, a.y, sh), 0.f);
        a.z = fmaxf(fmaf(sc, a.z, sh), 0.f);
        a.w = fmaxf(fmaf(sc, a.w, sh), 0.f);
        d.x = fmaxf(fmaf(sc, d.x, sh), 0.f);
        d.y = fmaxf(fmaf(sc, d.y, sh), 0.f);
        d.z = fmaxf(fmaf(sc, d.z, sh), 0.f);
        d.w = fmaxf(fmaf(sc, d.w, sh), 0.f);
        *(f32x4*)(bev + f) = a;
        *(f32x4*)(bev + f + 4) = d;
    } else {
        int t = (bid - NBN_BLK) * 256 + threadIdx.x;
        int f = t * 4;
        int bnc = f / DHW;
        int r1  = f - bnc * DHW;
        int d   = r1 / HW;
        int p   = r1 - d * HW;
        int y   = p / W_;
        int x   = p - y * W_;
        float ka = ws[WS_KINV + bnc * 3 + 0];
        float kb = ws[WS_KINV + bnc * 3 + 1];
        float kc = ws[WS_KINV + bnc * 3 + 2];
        float dep = depths[d];
        float base = fmaf(kb, (float)y, kc);
        f32x4 v;
        v.x = dep * fmaf(ka, (float)(x + 0), base);
        v.y = dep * fmaf(ka, (float)(x + 1), base);
        v.z = dep * fmaf(ka, (float)(x + 2), base);
        v.w = dep * fmaf(ka, (float)(x + 3), base);
        __builtin_nontemporal_store(v, (f32x4*)(out + f));
    }
}

extern "C" void kernel_launch(void* const* d_in, const int* in_sizes, int n_in,
                              void* d_out, int out_size, void* d_ws, size_t ws_size,
                              hipStream_t stream) {
    const float* K4     = (const float*)d_in[1];
    const float* vatt   = (const float*)d_in[3];
    const float* datt   = (const float*)d_in[4];
    const float* c1w    = (const float*)d_in[5];
    const float* c1b    = (const float*)d_in[6];
    const float* g1     = (const float*)d_in[7];
    const float* bb1    = (const float*)d_in[8];
    const float* c2w    = (const float*)d_in[9];
    const float* c2b    = (const float*)d_in[10];
    const float* g2     = (const float*)d_in[11];
    const float* bb2    = (const float*)d_in[12];
    const float* depths = (const float*)d_in[13];

    float* out = (float*)d_out;
    float* ws  = (float*)d_ws;
    char* base = (char*)d_out;
    // scratch inside pc region of d_out (k_tail's pc part overwrites it last)
    ushort_t* h1pm    = (ushort_t*)base;                        // 11.5 MB, [pix][64]
    float*    bevf    = (float*)(base + (32u << 20));           // 1.1 MB
    ushort_t* packedW = (ushort_t*)(base + (36u << 20));        // 72 KB
    float*    h2f     = out + PC_SIZE;                          // bev region (fp32)

    k_bevf<<<177, 256, 0, stream>>>(K4, datt, vatt, depths, ws, bevf);
    k_conv1<<<496, 256, 0, stream>>>(bevf, c1w, c1b, c2w, h1pm, packedW);
    k_stats<<<256, 256, 0, stream>>>(h1pm, ws);
    k_conv2<<<dim3(11, 32, 2), 256, 0, stream>>>(h1pm, packedW, c2b, g1, bb1, ws, h2f);
    k_tail<<<NBN_BLK + NPC_BLK, 256, 0, stream>>>(depths, ws, g2, bb2, out);
}